// Round 7
// baseline (220.544 us; speedup 1.0000x reference)
//
#include <hip/hip_runtime.h>
#include <math.h>

#define ALPHA 0.7f
#define EPSF  1e-7f

// clang ext_vector types so __builtin_nontemporal_load accepts them
typedef float f32x4 __attribute__((ext_vector_type(4)));
typedef int   i32x4 __attribute__((ext_vector_type(4)));

// focal element: pt = pos ? p : 1-p; lg = -log(pt) (inf -> 1e-7);
// f = (1-pt)^2 * lg; pos gets * ALPHA
// __logf -> v_log_f32; v_log_f32(0) = -inf so the inf->EPS path is preserved.
__device__ __forceinline__ float focal_elem(float p, int y) {
    const bool pos = (y == 1);
    const float pt = pos ? p : 1.0f - p;
    float lg = -__logf(pt);
    if (isinf(lg)) lg = EPSF;
    const float om = 1.0f - pt;
    float f = om * om * lg;
    return pos ? f * ALPHA : f;
}

__device__ __forceinline__ float focal4(const f32x4 pv, const i32x4 yv) {
    float a = focal_elem(pv.x, yv.x);
    a += focal_elem(pv.y, yv.y);
    a += focal_elem(pv.z, yv.z);
    a += focal_elem(pv.w, yv.w);
    return a;
}

template <int BLOCK>
__device__ __forceinline__ float block_reduce(float acc) {
    #pragma unroll
    for (int off = 32; off > 0; off >>= 1)
        acc += __shfl_down(acc, off, 64);
    __shared__ float smem[BLOCK / 64];
    const int lane = threadIdx.x & 63;
    const int wave = threadIdx.x >> 6;
    if (lane == 0) smem[wave] = acc;
    __syncthreads();
    float s = 0.0f;
    if (threadIdx.x == 0) {
        #pragma unroll
        for (int w = 0; w < BLOCK / 64; ++w) s += smem[w];
    }
    return s;
}

// R7: flat single-shot structure. Each thread issues ALL its nt loads (D=4
// float4+int4 pairs = 128 B) up front, computes once, block-reduces, exits.
// No pipeline loop -> the vmcnt window is never half-drained. Grid 6912
// blocks (27/CU) for sustained full residency (nt loads: every access is a
// real ~900cyc HBM miss; TLP is the latency-hiding resource).
// nt = no L2/L3 allocation: avoids the dirty-L3 churn from the harness
// input-restore that capped R0-R4 at ~2.6 TB/s effective.
template <int BLOCK, int D>
__global__ void __launch_bounds__(BLOCK, 4)
focal_partial(const float* __restrict__ p, const int* __restrict__ y,
              float* __restrict__ partial, long long n) {
    constexpr int VPB = BLOCK * D;  // float4s per block
    const long long n4 = n >> 2;
    const f32x4* __restrict__ p4 = (const f32x4*)p;
    const i32x4* __restrict__ y4 = (const i32x4*)y;
    const long long blk = (long long)blockIdx.x * VPB;
    const int t = threadIdx.x;

    float acc = 0.0f;
    if (blk + VPB <= n4) {
        const long long base = blk + t;
        f32x4 pv[D]; i32x4 yv[D];
        #pragma unroll
        for (int d = 0; d < D; ++d) {
            pv[d] = __builtin_nontemporal_load(&p4[base + d * BLOCK]);
            yv[d] = __builtin_nontemporal_load(&y4[base + d * BLOCK]);
        }
        #pragma unroll
        for (int d = 0; d < D; ++d) acc += focal4(pv[d], yv[d]);
    } else {
        // tail block (not hit for the bench shape: n4 % VPB == 0)
        for (long long i = blk + t; i < n4; i += BLOCK)
            acc += focal4(p4[i], y4[i]);
    }
    // scalar remainder (n % 4), done once by the last block
    if (blockIdx.x == gridDim.x - 1 && t == 0) {
        for (long long j = n4 << 2; j < n; ++j)
            acc += focal_elem(p[j], y[j]);
    }

    const float s = block_reduce<BLOCK>(acc);
    if (t == 0) partial[blockIdx.x] = s;
}

template <int BLOCK>
__global__ void __launch_bounds__(BLOCK)
focal_final(const float* __restrict__ partial, int nparts,
            float* __restrict__ out, long long n) {
    float acc = 0.0f;
    for (int i = threadIdx.x; i < nparts; i += BLOCK) acc += partial[i];
    const float s = block_reduce<BLOCK>(acc);
    if (threadIdx.x == 0) out[0] = s / (float)n;
}

extern "C" void kernel_launch(void* const* d_in, const int* in_sizes, int n_in,
                              void* d_out, int out_size, void* d_ws, size_t ws_size,
                              hipStream_t stream) {
    const float* p = (const float*)d_in[0];
    const int*   y = (const int*)d_in[1];
    float* out = (float*)d_out;
    float* partial = (float*)d_ws;

    const long long n = (long long)in_sizes[0];
    constexpr int BLOCK = 256;
    constexpr int D = 4;  // 8 nt loads (128 B) in flight per thread, all at once
    constexpr int VPB = BLOCK * D;  // 1024 float4s per block
    const long long n4 = n >> 2;
    int nblocks = (int)((n4 + VPB - 1) / VPB);  // 6912 for n=28,311,552 (exact)
    if (nblocks < 1) nblocks = 1;

    focal_partial<BLOCK, D><<<nblocks, BLOCK, 0, stream>>>(p, y, partial, n);
    focal_final<BLOCK><<<1, BLOCK, 0, stream>>>(partial, nblocks, out, n);
}